// Round 13
// baseline (285.140 us; speedup 1.0000x reference)
//
#include <hip/hip_runtime.h>

#define FDIM 128
#define LN_EPS 1e-5f
#define BSH 9              // 512 nodes per bucket
#define EPB 2048           // edges per block in bucket passes

typedef short short8 __attribute__((ext_vector_type(8)));
typedef float f32x4 __attribute__((ext_vector_type(4)));

__device__ __forceinline__ ushort f2bf(float f) {
    uint u = __float_as_uint(f);
    u += 0x7fff + ((u >> 16) & 1);      // RNE
    return (ushort)(u >> 16);
}
__device__ __forceinline__ float bflo(uint u) { return __uint_as_float(u << 16); }
__device__ __forceinline__ float bfhi(uint u) { return __uint_as_float(u & 0xffff0000u); }
__device__ __forceinline__ float bfs(short s) { return __uint_as_float(((uint)(ushort)s) << 16); }

// ---------------- bucketed CSR build (no global atomics) — proven R12 ----------------
__global__ __launch_bounds__(256) void k_bcount(const int* __restrict__ dst,
                                                uint* __restrict__ mat, int nbk, int E) {
    __shared__ uint cnt[512];
    int t = threadIdx.x;
    for (int i = t; i < nbk; i += 256) cnt[i] = 0;
    __syncthreads();
    int base = blockIdx.x * EPB, end = min(base + EPB, E);
    for (int e = base + t; e < end; e += 256)
        atomicAdd(&cnt[(uint)dst[e] >> BSH], 1u);
    __syncthreads();
    for (int i = t; i < nbk; i += 256) mat[(size_t)blockIdx.x * nbk + i] = cnt[i];
}

__global__ __launch_bounds__(1024) void k_colscan(uint* __restrict__ mat,
                                                  uint* __restrict__ btot, int nbk, int nblk) {
    __shared__ uint s[1024];
    int b = blockIdx.x, t = threadIdx.x;
    uint run = 0;
    for (int base = 0; base < nblk; base += 1024) {
        int i = base + t;
        uint v = (i < nblk) ? mat[(size_t)i * nbk + b] : 0;
        s[t] = v;
        __syncthreads();
        for (int off = 1; off < 1024; off <<= 1) {
            uint u = (t >= off) ? s[t - off] : 0;
            __syncthreads();
            s[t] += u;
            __syncthreads();
        }
        if (i < nblk) mat[(size_t)i * nbk + b] = run + s[t] - v;
        run += s[1023];
        __syncthreads();
    }
    if (t == 0) btot[b] = run;
}

__global__ __launch_bounds__(256) void k_bscatter(const int* __restrict__ src,
                                                  const int* __restrict__ dst,
                                                  const uint* __restrict__ mat,
                                                  const uint* __restrict__ btot,
                                                  uint* __restrict__ ebuf, int nbk, int E) {
    __shared__ uint cur[512];
    __shared__ uint ps[256];
    int t = threadIdx.x;
    uint v = (t < nbk) ? btot[t] : 0;
    ps[t] = v;
    __syncthreads();
    for (int off = 1; off < 256; off <<= 1) {
        uint u = (t >= off) ? ps[t - off] : 0;
        __syncthreads();
        ps[t] += u;
        __syncthreads();
    }
    if (t < nbk) cur[t] = (ps[t] - v) + mat[(size_t)blockIdx.x * nbk + t];
    __syncthreads();
    int base = blockIdx.x * EPB, end = min(base + EPB, E);
    for (int e = base + t; e < end; e += 256) {
        uint d = (uint)dst[e];
        uint off = atomicAdd(&cur[d >> BSH], 1u);
        ebuf[off] = ((d & 511u) << 17) | (uint)src[e];
    }
}

__global__ __launch_bounds__(256) void k_bdeg(const uint* __restrict__ ebuf,
                                              const uint* __restrict__ btot,
                                              int* __restrict__ deg, float* __restrict__ dinv,
                                              uint* __restrict__ padtot, int N, int nbk) {
    __shared__ uint cnt[512];
    __shared__ uint ps[256];
    __shared__ uint begs;
    int b = blockIdx.x, t = threadIdx.x;
    for (int i = t; i < 512; i += 256) cnt[i] = 0;
    uint v = (t < nbk) ? btot[t] : 0;
    ps[t] = v;
    __syncthreads();
    for (int off = 1; off < 256; off <<= 1) {
        uint u = (t >= off) ? ps[t - off] : 0;
        __syncthreads();
        ps[t] += u;
        __syncthreads();
    }
    if (t == b) begs = ps[t] - v;
    __syncthreads();
    uint beg = begs, cn = btot[b];
    for (uint i = t; i < cn; i += 256) atomicAdd(&cnt[ebuf[beg + i] >> 17], 1u);
    __syncthreads();
    int n0 = b << BSH;
    uint loc = 0;
    for (int i = t; i < 512; i += 256) {
        int n = n0 + i;
        if (n < N) {
            uint dg = cnt[i];
            deg[n] = (int)dg;
            dinv[n] = rsqrtf((float)dg + 1.0f);
            loc += (dg + 7u) & ~7u;
        }
    }
    ps[t] = loc;
    __syncthreads();
    for (int off = 128; off >= 1; off >>= 1) {
        if (t < off) ps[t] += ps[t + off];
        __syncthreads();
    }
    if (t == 0) padtot[b] = ps[0];
}

__device__ __forceinline__ void bfill_body(const uint* __restrict__ ebuf,
                                           const uint* __restrict__ btot,
                                           const uint* __restrict__ padtot,
                                           const int* __restrict__ deg,
                                           int* __restrict__ rowptr, int* __restrict__ col,
                                           int N, int nbk, int b) {
    __shared__ uint ps[256];
    __shared__ uint curf[512];
    __shared__ uint sc0, sc1;
    int t = threadIdx.x;
    uint v = (t < nbk) ? btot[t] : 0;
    ps[t] = v;
    __syncthreads();
    for (int off = 1; off < 256; off <<= 1) {
        uint u = (t >= off) ? ps[t - off] : 0;
        __syncthreads();
        ps[t] += u;
        __syncthreads();
    }
    if (t == b) sc0 = ps[t] - v;
    __syncthreads();
    uint w = (t < nbk) ? padtot[t] : 0;
    ps[t] = w;
    __syncthreads();
    for (int off = 1; off < 256; off <<= 1) {
        uint u = (t >= off) ? ps[t - off] : 0;
        __syncthreads();
        ps[t] += u;
        __syncthreads();
    }
    if (t == b) sc1 = ps[t] - w;
    if (b == nbk - 1 && t == nbk - 1) rowptr[N] = (int)ps[t];
    __syncthreads();
    uint beg = sc0, cn = btot[b], base = sc1;
    int n0 = b << BSH;
    int nA = n0 + 2 * t, nB = nA + 1;
    uint dA = (nA < N) ? (uint)deg[nA] : 0;
    uint dB = (nB < N) ? (uint)deg[nB] : 0;
    uint pA = (dA + 7u) & ~7u, pB = (dB + 7u) & ~7u;
    uint pair = pA + pB;
    ps[t] = pair;
    __syncthreads();
    for (int off = 1; off < 256; off <<= 1) {
        uint u = (t >= off) ? ps[t - off] : 0;
        __syncthreads();
        ps[t] += u;
        __syncthreads();
    }
    uint pex = ps[t] - pair;
    uint rA = base + pex, rB = rA + pA;
    curf[2 * t] = rA; curf[2 * t + 1] = rB;
    if (nA < N) rowptr[nA] = (int)rA;
    if (nB < N) rowptr[nB] = (int)rB;
    if (nA < N) for (uint k = dA; k < pA; ++k) col[rA + k] = N;
    if (nB < N) for (uint k = dB; k < pB; ++k) col[rB + k] = N;
    __syncthreads();
    for (uint i = t; i < cn; i += 256) {
        uint e = ebuf[beg + i];
        uint p = atomicAdd(&curf[e >> 17], 1u);
        col[p] = (int)(e & 0x1FFFFu);
    }
}

// -------- weights -> W^T bf16 + zero sentinel rows (row N of each H slice) --------
__global__ void k_wt2(const float* __restrict__ W1, const float* __restrict__ W2,
                      ushort* __restrict__ WT1, ushort* __restrict__ WT2,
                      ushort* __restrict__ H, int N) {
    int b = blockIdx.x, k = threadIdx.x;
    if (b < 128)      WT1[b * 128 + k] = f2bf(W1[k * 128 + b]);
    else if (b < 256) WT2[(b - 128) * 128 + k] = f2bf(W2[k * 128 + (b - 128)]);
    else if (k < 64) {                      // 8 slices x 16 ushorts = 64 uints
        int s = k >> 3, j = k & 7;
        ((uint*)(H + (size_t)s * (N + 1) * 16 + (size_t)N * 16))[j] = 0;
    }
}

// -------- GEMM: H'[slice][r][16] = dinv[r]*(X[r,:]@W), slice-major bf16 out --------
// MODE 0: X = fp32 rows.  MODE 1: X = sliced bf16 A + fused LayerNorm (stats,gamma,beta).
template <int MODE>
__device__ __forceinline__ void gemm_body(char* sXb, char* sWb,
                                          const void* __restrict__ Xin,
                                          const ushort* __restrict__ WT,
                                          const float* __restrict__ dinv,
                                          const float2* __restrict__ stats,
                                          const float* __restrict__ gamma,
                                          const float* __restrict__ beta,
                                          ushort* __restrict__ H, int N, int bid) {
    int t = threadIdx.x;
    int w = t >> 6, lane = t & 63;
    int cl = lane & 15, kq = lane >> 4;
    int base = bid * 64;

    const short8* Wg = (const short8*)WT;
#pragma unroll
    for (int k = 0; k < 8; ++k) {
        int idx = t + k * 256;
        int c = idx >> 4, ch = idx & 15;
        *(short8*)(sWb + c * 256 + ((ch * 16) ^ ((c & 7) << 4))) = Wg[idx];
    }

    if constexpr (MODE == 0) {
        const float4* X4 = (const float4*)Xin;
        size_t lim = (size_t)N * 32 - 1;
#pragma unroll
        for (int k = 0; k < 8; ++k) {
            int idx = t + k * 256;
            size_t gi = (size_t)base * 32 + idx;
            float4 v = X4[gi < lim ? gi : lim];
            ushort4 o;
            o.x = f2bf(v.x); o.y = f2bf(v.y); o.z = f2bf(v.z); o.w = f2bf(v.w);
            int row = idx >> 5, b8 = (idx & 31) * 8;
            *(ushort4*)(sXb + row * 256 + (b8 ^ ((row & 7) << 4))) = o;
        }
    } else {
        const short8* A8 = (const short8*)Xin;          // sliced: [slice][(N+1) rows][2 short8]
        size_t srows = (size_t)(N + 1) * 2;
#pragma unroll
        for (int k = 0; k < 4; ++k) {
            int idx = t + k * 256;                      // 64 rows x 16 chunks
            int row = idx >> 4, cc = idx & 15;
            int rc = min(base + row, N - 1);
            short8 v = A8[(size_t)(cc >> 1) * srows + (size_t)rc * 2 + (cc & 1)];
            float2 ms = stats[rc];
            short8 o;
#pragma unroll
            for (int j = 0; j < 8; ++j) {
                int f = cc * 8 + j;
                float val = (bfs(v[j]) - ms.x) * ms.y * gamma[f] + beta[f];
                o[j] = (short)f2bf(val);
            }
            *(short8*)(sXb + row * 256 + ((cc * 16) ^ ((row & 7) << 4))) = o;
        }
    }
    __syncthreads();

    int rl = w * 16 + cl;
    short8 b0, b1, b2, b3;
#pragma unroll
    for (int kt = 0; kt < 4; ++kt) {
        short8 v = *(const short8*)(sXb + rl * 256 + ((kt * 64 + kq * 16) ^ ((rl & 7) << 4)));
        if (kt == 0) b0 = v; else if (kt == 1) b1 = v; else if (kt == 2) b2 = v; else b3 = v;
    }

    int r = base + rl;
    bool ok = r < N;
    float di = dinv[min(r, N - 1)];
#pragma unroll
    for (int nt = 0; nt < 8; ++nt) {
        int c = nt * 16 + cl;
        int sw = (c & 7) << 4;
        f32x4 acc = {0.f, 0.f, 0.f, 0.f};
        acc = __builtin_amdgcn_mfma_f32_16x16x32_bf16(
            *(const short8*)(sWb + c * 256 + ((0 * 64 + kq * 16) ^ sw)), b0, acc, 0, 0, 0);
        acc = __builtin_amdgcn_mfma_f32_16x16x32_bf16(
            *(const short8*)(sWb + c * 256 + ((1 * 64 + kq * 16) ^ sw)), b1, acc, 0, 0, 0);
        acc = __builtin_amdgcn_mfma_f32_16x16x32_bf16(
            *(const short8*)(sWb + c * 256 + ((2 * 64 + kq * 16) ^ sw)), b2, acc, 0, 0, 0);
        acc = __builtin_amdgcn_mfma_f32_16x16x32_bf16(
            *(const short8*)(sWb + c * 256 + ((3 * 64 + kq * 16) ^ sw)), b3, acc, 0, 0, 0);
        if (ok) {
            ushort4 o;
            o.x = f2bf(acc[0] * di); o.y = f2bf(acc[1] * di);
            o.z = f2bf(acc[2] * di); o.w = f2bf(acc[3] * di);
            // slice-major: slice nt covers features nt*16..+15
            *(ushort4*)(H + (size_t)nt * (N + 1) * 16 + (size_t)r * 16 + kq * 4) = o;
        }
    }
}

template <int MODE>
__global__ __launch_bounds__(256) void k_gemm(const void* __restrict__ Xin,
                                              const ushort* __restrict__ WT,
                                              const float* __restrict__ dinv,
                                              const float2* __restrict__ stats,
                                              const float* __restrict__ gamma,
                                              const float* __restrict__ beta,
                                              ushort* __restrict__ H, int N) {
    __shared__ ushort sX[64 * 128];
    __shared__ ushort sW[128 * 128];
    gemm_body<MODE>((char*)sX, (char*)sW, Xin, WT, dinv, stats, gamma, beta, H, N, blockIdx.x);
}

// -------- MEGA: blocks [0,ngemm) = gemm1 (fp32 in), blocks [ngemm,ngemm+nbk) = D2 fill --------
__global__ __launch_bounds__(256) void k_mega(const void* __restrict__ Xin,
                                              const ushort* __restrict__ WT,
                                              const float* __restrict__ dinv,
                                              ushort* __restrict__ H, int N, int ngemm,
                                              const uint* __restrict__ ebuf,
                                              const uint* __restrict__ btot,
                                              const uint* __restrict__ padtot,
                                              const int* __restrict__ deg,
                                              int* __restrict__ rowptr,
                                              int* __restrict__ col, int nbk) {
    __shared__ ushort sX[64 * 128];
    __shared__ ushort sW[128 * 128];
    if (blockIdx.x < (uint)ngemm) {
        gemm_body<0>((char*)sX, (char*)sW, Xin, WT, dinv, nullptr, nullptr, nullptr, H, N, blockIdx.x);
    } else {
        bfill_body(ebuf, btot, padtot, deg, rowptr, col, N, nbk, blockIdx.x - ngemm);
    }
}

// ------- sliced aggregate: slice = blockIdx&7 (round-robin XCD alignment), -------
// 4 lanes/node (uint2 = 4 features), bias+ReLU, write sliced A + LN partial sums.
__global__ __launch_bounds__(256) void k_agg_s(const ushort* __restrict__ Hs,
                                               const int* __restrict__ rowptr,
                                               const int* __restrict__ col,
                                               const float* __restrict__ dinv,
                                               const float* __restrict__ bias,
                                               ushort* __restrict__ Aout,
                                               float2* __restrict__ pstat, int N) {
    int s = blockIdx.x & 7;
    int chunk = blockIdx.x >> 3;
    int w = threadIdx.x >> 6, lane = threadIdx.x & 63;
    int g = lane >> 2, fl = lane & 3;       // group of 4 lanes per node
    int node = chunk * 64 + w * 16 + g;
    bool valid = node < N;
    int nodec = valid ? node : N - 1;

    const uint2* Hu = (const uint2*)(Hs + (size_t)s * (N + 1) * 16);   // row = 4 uint2
    float di = dinv[nodec];
    uint2 hv = Hu[(size_t)nodec * 4 + fl];
    float a0 = bflo(hv.x), a1 = bfhi(hv.x), a2 = bflo(hv.y), a3 = bfhi(hv.y);

    int beg = rowptr[nodec];
    int deg8 = rowptr[nodec + 1] - beg;     // multiple of 8
    const int* cp = col + beg;

    for (int i = 0; i < deg8; i += 8) {
        int e0 = cp[i + 0], e1 = cp[i + 1], e2 = cp[i + 2], e3 = cp[i + 3];
        int e4 = cp[i + 4], e5 = cp[i + 5], e6 = cp[i + 6], e7 = cp[i + 7];
        uint2 u0 = Hu[(size_t)e0 * 4 + fl];
        uint2 u1 = Hu[(size_t)e1 * 4 + fl];
        uint2 u2 = Hu[(size_t)e2 * 4 + fl];
        uint2 u3 = Hu[(size_t)e3 * 4 + fl];
        uint2 u4 = Hu[(size_t)e4 * 4 + fl];
        uint2 u5 = Hu[(size_t)e5 * 4 + fl];
        uint2 u6 = Hu[(size_t)e6 * 4 + fl];
        uint2 u7 = Hu[(size_t)e7 * 4 + fl];
        a0 += bflo(u0.x); a1 += bfhi(u0.x); a2 += bflo(u0.y); a3 += bfhi(u0.y);
        a0 += bflo(u1.x); a1 += bfhi(u1.x); a2 += bflo(u1.y); a3 += bfhi(u1.y);
        a0 += bflo(u2.x); a1 += bfhi(u2.x); a2 += bflo(u2.y); a3 += bfhi(u2.y);
        a0 += bflo(u3.x); a1 += bfhi(u3.x); a2 += bflo(u3.y); a3 += bfhi(u3.y);
        a0 += bflo(u4.x); a1 += bfhi(u4.x); a2 += bflo(u4.y); a3 += bfhi(u4.y);
        a0 += bflo(u5.x); a1 += bfhi(u5.x); a2 += bflo(u5.y); a3 += bfhi(u5.y);
        a0 += bflo(u6.x); a1 += bfhi(u6.x); a2 += bflo(u6.y); a3 += bfhi(u6.y);
        a0 += bflo(u7.x); a1 += bfhi(u7.x); a2 += bflo(u7.y); a3 += bfhi(u7.y);
    }

    float4 bb = ((const float4*)bias)[s * 4 + fl];     // features s*16 + fl*4 ..+3
    a0 = fmaxf(fmaf(a0, di, bb.x), 0.f);
    a1 = fmaxf(fmaf(a1, di, bb.y), 0.f);
    a2 = fmaxf(fmaf(a2, di, bb.z), 0.f);
    a3 = fmaxf(fmaf(a3, di, bb.w), 0.f);

    float s1 = (a0 + a1) + (a2 + a3);
    float s2 = (a0 * a0 + a1 * a1) + (a2 * a2 + a3 * a3);
    s1 += __shfl_xor(s1, 1); s1 += __shfl_xor(s1, 2);  // 4-lane group reduce
    s2 += __shfl_xor(s2, 1); s2 += __shfl_xor(s2, 2);

    if (!valid) return;
    uint2 o;
    o.x = (uint)f2bf(a0) | ((uint)f2bf(a1) << 16);
    o.y = (uint)f2bf(a2) | ((uint)f2bf(a3) << 16);
    ((uint2*)(Aout + (size_t)s * (N + 1) * 16))[(size_t)node * 4 + fl] = o;
    if (fl == 0) pstat[(size_t)node * 8 + s] = make_float2(s1, s2);
}

// per-node LN stats from 8 slice partials
__global__ void k_lnstat(const float2* __restrict__ pstat, float2* __restrict__ stats, int N) {
    int i = blockIdx.x * 256 + threadIdx.x;
    if (i < N) {
        float s1 = 0.f, s2 = 0.f;
#pragma unroll
        for (int s = 0; s < 8; ++s) {
            float2 p = pstat[(size_t)i * 8 + s];
            s1 += p.x; s2 += p.y;
        }
        float mu = s1 * (1.f / 128.f);
        float var = s2 * (1.f / 128.f) - mu * mu;
        stats[i] = make_float2(mu, rsqrtf(var + LN_EPS));
    }
}

// final LN apply: sliced bf16 A2 -> fp32 [node][128]
__global__ void k_lnapply(const ushort* __restrict__ A, const float2* __restrict__ stats,
                          const float* __restrict__ gamma, const float* __restrict__ beta,
                          float* __restrict__ out, int N) {
    int i = blockIdx.x * 256 + threadIdx.x;
    if (i >= N * 16) return;
    int node = i >> 4, cc = i & 15;
    const short8* A8 = (const short8*)A;
    size_t srows = (size_t)(N + 1) * 2;
    short8 v = A8[(size_t)(cc >> 1) * srows + (size_t)node * 2 + (cc & 1)];
    float2 ms = stats[node];
    float4 o0, o1;
    o0.x = (bfs(v[0]) - ms.x) * ms.y * gamma[cc * 8 + 0] + beta[cc * 8 + 0];
    o0.y = (bfs(v[1]) - ms.x) * ms.y * gamma[cc * 8 + 1] + beta[cc * 8 + 1];
    o0.z = (bfs(v[2]) - ms.x) * ms.y * gamma[cc * 8 + 2] + beta[cc * 8 + 2];
    o0.w = (bfs(v[3]) - ms.x) * ms.y * gamma[cc * 8 + 3] + beta[cc * 8 + 3];
    o1.x = (bfs(v[4]) - ms.x) * ms.y * gamma[cc * 8 + 4] + beta[cc * 8 + 4];
    o1.y = (bfs(v[5]) - ms.x) * ms.y * gamma[cc * 8 + 5] + beta[cc * 8 + 5];
    o1.z = (bfs(v[6]) - ms.x) * ms.y * gamma[cc * 8 + 6] + beta[cc * 8 + 6];
    o1.w = (bfs(v[7]) - ms.x) * ms.y * gamma[cc * 8 + 7] + beta[cc * 8 + 7];
    ((float4*)out)[(size_t)node * 32 + cc * 2]     = o0;
    ((float4*)out)[(size_t)node * 32 + cc * 2 + 1] = o1;
}

// ---------------- launch ----------------
extern "C" void kernel_launch(void* const* d_in, const int* in_sizes, int n_in,
                              void* d_out, int out_size, void* d_ws, size_t ws_size,
                              hipStream_t stream) {
    const float* x  = (const float*)d_in[0];
    const int*   ei = (const int*)d_in[1];
    const float* W1 = (const float*)d_in[2];
    const float* b1 = (const float*)d_in[3];
    const float* W2 = (const float*)d_in[4];
    const float* b2 = (const float*)d_in[5];
    const float* g1 = (const float*)d_in[6];
    const float* be1 = (const float*)d_in[7];
    const float* g2 = (const float*)d_in[8];
    const float* be2 = (const float*)d_in[9];

    int N = in_sizes[0] / FDIM;
    int E = in_sizes[1] / 2;
    const int* srcp = ei;
    const int* dstp = ei + E;
    float* out = (float*)d_out;

    char* w = (char*)d_ws;
    size_t off = 0;
    auto take = [&](size_t bytes) {
        void* p = w + off;
        off = (off + bytes + 255) & ~(size_t)255;
        return p;
    };
    int nbk  = (N + 511) >> BSH;
    int nblk = (E + EPB - 1) / EPB;

    ushort* H   = (ushort*)take((size_t)(N + 1) * FDIM * sizeof(ushort)); // sliced h'
    ushort* A   = (ushort*)take((size_t)(N + 1) * FDIM * sizeof(ushort)); // sliced pre-LN acts
    // aliases inside A (both dead before A's first write in agg1):
    uint* ebuf  = (uint*)A;
    uint* mat   = (uint*)((char*)A + (((size_t)E * 4 + 255) & ~(size_t)255));
    ushort* WT1 = (ushort*)take(128 * 128 * sizeof(ushort));
    ushort* WT2 = (ushort*)take(128 * 128 * sizeof(ushort));
    uint* btot   = (uint*)take((size_t)nbk * sizeof(uint));
    uint* padtot = (uint*)take((size_t)nbk * sizeof(uint));
    int* deg     = (int*)take((size_t)N * sizeof(int));
    int* rowptr  = (int*)take((size_t)(N + 1) * sizeof(int));
    int* colb    = (int*)take((size_t)(E + 7 * (size_t)N + 1024) * sizeof(int));
    float* dinv  = (float*)take((size_t)N * sizeof(float));
    float2* stats = (float2*)take((size_t)N * sizeof(float2));
    float2* pstat = (float2*)d_out;          // scratch in d_out; dead before final write
    (void)ws_size;

    int ngemm = (N + 63) / 64;
    int naggb = 8 * ((N + 63) / 64);

    // weights -> W^T bf16 + zero H sentinel rows
    k_wt2<<<257, 128, 0, stream>>>(W1, W2, WT1, WT2, H, N);

    // bucketed CSR build (no global atomics)
    k_bcount<<<nblk, 256, 0, stream>>>(dstp, mat, nbk, E);
    k_colscan<<<nbk, 1024, 0, stream>>>(mat, btot, nbk, nblk);
    k_bscatter<<<nblk, 256, 0, stream>>>(srcp, dstp, mat, btot, ebuf, nbk, E);
    k_bdeg<<<nbk, 256, 0, stream>>>(ebuf, btot, deg, dinv, padtot, N, nbk);

    // MEGA: gemm1 (fp32 in) || D2 bucket fill
    k_mega<<<ngemm + nbk, 256, 0, stream>>>(x, WT1, dinv, H, N, ngemm,
                                            ebuf, btot, padtot, deg, rowptr, colb, nbk);

    // layer 1: sliced agg -> LN stats (LN applied inside gemm2 staging)
    k_agg_s<<<naggb, 256, 0, stream>>>(H, rowptr, colb, dinv, b1, A, pstat, N);
    k_lnstat<<<(N + 255) / 256, 256, 0, stream>>>(pstat, stats, N);

    // layer 2: gemm (sliced A + LN fused) -> sliced agg -> LN stats -> final apply
    k_gemm<1><<<ngemm, 256, 0, stream>>>(A, WT2, dinv, stats, g1, be1, H, N);
    k_agg_s<<<naggb, 256, 0, stream>>>(H, rowptr, colb, dinv, b2, A, pstat, N);
    k_lnstat<<<(N + 255) / 256, 256, 0, stream>>>(pstat, stats, N);
    k_lnapply<<<(N * 16 + 255) / 256, 256, 0, stream>>>(A, stats, g2, be2, out, N);
}